// Round 24
// baseline (269.027 us; speedup 1.0000x reference)
//
#include <hip/hip_runtime.h>

#define NU 100000
#define NI 200000
#define NN 300000
#define NNZE 1200000
#define D 64
#define OS 256   // (L+1)*D output row stride
#define EW 24    // total slots: 16 in ecv16 (zeroed) + 8 in ecvT

typedef __attribute__((ext_vector_type(8))) short s16x8;
typedef __attribute__((ext_vector_type(4))) float f32x4;
typedef __attribute__((ext_vector_type(2))) unsigned long long u64x2;

__device__ __forceinline__ float bf2f(unsigned short u) {
    return __uint_as_float(((unsigned int)u) << 16);
}
__device__ __forceinline__ unsigned short f2bf(float f) {
    unsigned int u = __float_as_uint(f);
    u = (u + 0x7FFF + ((u >> 16) & 1)) >> 16;   // RNE
    return (unsigned short)u;
}

// -- concat -> out chunk0 + ebf; fused ELL scatter (first 1.2M threads);
//    blocks 0-5 additionally pre-transpose W --------------------------------
__global__ void k_concat(const float* __restrict__ ue, const float* __restrict__ ie,
                         float* __restrict__ out, unsigned short* __restrict__ ebf,
                         const float* __restrict__ Wc, const float* __restrict__ We,
                         unsigned short* __restrict__ wbf,
                         const int* __restrict__ rows, const int* __restrict__ cols,
                         const float* __restrict__ vals, int* __restrict__ cnt,
                         unsigned long long* __restrict__ ecv16,
                         unsigned long long* __restrict__ ecvT) {
    int idx = blockIdx.x * blockDim.x + threadIdx.x;
    // ELL scatter (latency-bound, hides under the BW-bound concat stream)
    if (idx < NNZE) {
        int r = rows[idx];
        int pos = atomicAdd(&cnt[r], 1);
        // low 32: byte offset into ebf (col*D*2 = col*128); high 32: val bits
        unsigned long long packed = (unsigned int)(cols[idx] * 128)
            | ((unsigned long long)(unsigned int)__float_as_int(vals[idx]) << 32);
        if (pos < 16)      ecv16[(size_t)r * 16 + pos] = packed;
        else if (pos < EW) ecvT[(size_t)r * 8 + (pos - 16)] = packed;
    }
    if (idx < NN * 16) {
        int n = idx >> 4, c = idx & 15;
        float4 v;
        if (n < NU) v = ((const float4*)(ue + (size_t)n * D))[c];
        else        v = ((const float4*)(ie + (size_t)(n - NU) * D))[c];
        f32x4 vv = {v.x, v.y, v.z, v.w};
        __builtin_nontemporal_store(vv, (f32x4*)(out + (size_t)n * OS) + c);
        ushort4 b;
        b.x = f2bf(v.x); b.y = f2bf(v.y); b.z = f2bf(v.z); b.w = f2bf(v.w);
        *(ushort4*)(ebf + (size_t)n * D + c * 4) = b;
    }
    // W pre-transpose -> swizzled bf16 images (6 blocks, independent work)
    if (blockIdx.x < 6) {
        int lm = blockIdx.x;
        int l = lm >> 1, m = lm & 1;
        const float* W = (m ? We : Wc) + l * 4096;
        unsigned short* dst = wbf + lm * 4096;
        int tid = threadIdx.x;
        int base = tid * 16;
        int k = base >> 6, n = base & 63;
        #pragma unroll
        for (int i = 0; i < 4; i++) {
            float4 v = *(const float4*)(W + k * 64 + n + i * 4);
            #pragma unroll
            for (int j = 0; j < 4; j++) {
                int col = n + i * 4 + j;
                int byteoff = (col * 128 + k * 2) ^ ((col & 7) << 4);
                float fv = (j == 0) ? v.x : (j == 1) ? v.y : (j == 2) ? v.z : v.w;
                *(unsigned short*)((char*)dst + byteoff) = f2bf(fv);
            }
        }
    }
}

// ---------------- fused layer: ELL SpMM (8 lanes x 16B) + MFMA dense ---------
template<bool LAST>
__global__ __launch_bounds__(256, 4) void k_fused(
    const int* __restrict__ cnt, const unsigned long long* __restrict__ ecv16,
    const unsigned long long* __restrict__ ecvT,
    const unsigned short* __restrict__ ebf_in, unsigned short* __restrict__ ebf_out,
    const unsigned short* __restrict__ wsrc,
    const float* __restrict__ bc, const float* __restrict__ be,
    float* __restrict__ outN) {
    __shared__ __align__(16) unsigned short sWT[2][64 * 64];  // W^T; later f32 scratch
    __shared__ __align__(16) unsigned short sS[64 * 64];      // side tile; later bf16 scratch

    int tid = threadIdx.x;
    int n0 = blockIdx.x * 64;
    int grp = tid >> 3, lane8 = tid & 7;    // 32 groups x 8 lanes; 2 rows/group

    // deg load issued here; its VALUE only matters at the ~1e-6 tail branch
    int R0 = n0 + grp * 2;
    int deg[2];
    #pragma unroll
    for (int r = 0; r < 2; r++) {
        int rr = R0 + r;
        deg[r] = (rr < NN) ? cnt[rr] : 0;
    }

    // stage W: linear 16KB vector copy (swizzle baked into the image)
    {
        unsigned short* dst = &sWT[0][0];
        #pragma unroll
        for (int i = 0; i < 4; i++) {
            int idx = i * 2048 + tid * 8;
            *(s16x8*)(dst + idx) = *(const s16x8*)(wsrc + idx);
        }
    }

    // SpMM: 2 rows/group; 16 UNCONDITIONAL zero-padded slots per row ->
    // all metadata + all 16 gathers in flight with no deg dependence.
    {
        const char* ebase_c = (const char*)ebf_in;
        #pragma unroll
        for (int rr = 0; rr < 2; rr++) {
            int lrow = grp * 2 + rr;
            float a[8];
            #pragma unroll
            for (int j = 0; j < 8; j++) a[j] = 0.f;

            int rclamp = (R0 + rr) < NN ? (R0 + rr) : (NN - 1);
            const unsigned long long* b16 = ecv16 + (size_t)rclamp * 16;

            unsigned int boff[16];
            float v[16];
            {   // branchless 128B metadata read -> 8x16B loads
                #pragma unroll
                for (int p = 0; p < 8; p++) {
                    u64x2 pr = *(const u64x2*)(b16 + 2 * p);
                    boff[2 * p]     = (unsigned int)(pr.x & 0xFFFFFFFFu);
                    v[2 * p]        = __int_as_float((int)(pr.x >> 32));
                    boff[2 * p + 1] = (unsigned int)(pr.y & 0xFFFFFFFFu);
                    v[2 * p + 1]    = __int_as_float((int)(pr.y >> 32));
                }
            }
            s16x8 gg[16];
            #pragma unroll
            for (int k = 0; k < 16; k++)
                gg[k] = *(const s16x8*)(ebase_c + boff[k] + lane8 * 16);
            #pragma unroll
            for (int k = 0; k < 16; k++)
                #pragma unroll
                for (int j = 0; j < 8; j++)
                    a[j] += v[k] * bf2f((unsigned short)gg[k][j]);

            // ultra-rare tail (P(deg>16) ~ 1e-6 per row)
            int dg = deg[rr] > EW ? EW : deg[rr];
            if (dg > 16) {
                const unsigned long long* bt = ecvT + (size_t)rclamp * 8;
                #pragma unroll
                for (int k = 0; k < 8; k++) {
                    unsigned long long ek = (16 + k < dg) ? bt[k] : 0ull;
                    unsigned int bo = (unsigned int)(ek & 0xFFFFFFFFu);
                    float vv = __int_as_float((int)(ek >> 32));
                    s16x8 g = *(const s16x8*)(ebase_c + bo + lane8 * 16);
                    #pragma unroll
                    for (int j = 0; j < 8; j++)
                        a[j] += vv * bf2f((unsigned short)g[j]);
                }
            }

            s16x8 r8;
            #pragma unroll
            for (int j = 0; j < 8; j++) r8[j] = (short)f2bf(a[j]);
            int byteoff = (lrow * 128 + lane8 * 16) ^ ((lrow & 7) << 4);
            *(s16x8*)((char*)&sS[0] + byteoff) = r8;
        }
    }

    int wid = tid >> 6, lane = tid & 63;
    int lg = lane >> 4, lr = lane & 15;

    __syncthreads();   // sS (and sWT) ready

    int rowA = n0 + wid * 16 + lr;
    int rowAc = rowA < NN ? rowA : NN - 1;
    size_t abase = (size_t)rowAc * D;
    s16x8 ef[2];
    ef[0] = *(const s16x8*)(ebf_in + abase + lg * 8);
    ef[1] = *(const s16x8*)(ebf_in + abase + 32 + lg * 8);

    f32x4 acc[4];
    #pragma unroll
    for (int c = 0; c < 4; c++) {
        float bj = bc[c * 16 + lr] + be[c * 16 + lr];
        acc[c] = (f32x4){bj, bj, bj, bj};
    }

    int lrowA = wid * 16 + lr;
    s16x8 sf[2], wf[2];
    #pragma unroll
    for (int kb = 0; kb < 2; kb++) {
        int byteoff = (lrowA * 128 + (kb * 32 + lg * 8) * 2) ^ ((lrowA & 7) << 4);
        sf[kb] = *(const s16x8*)((const char*)&sS[0] + byteoff);
        #pragma unroll
        for (int j = 0; j < 8; j++) {
            float p = bf2f((unsigned short)sf[kb][j]) * bf2f((unsigned short)ef[kb][j]);
            wf[kb][j] = (short)f2bf(p);
        }
    }

    #pragma unroll
    for (int c = 0; c < 4; c++) {
        #pragma unroll
        for (int kb = 0; kb < 2; kb++) {
            int row = c * 16 + lr;
            int byteoff = (row * 128 + (kb * 32 + lg * 8) * 2) ^ ((row & 7) << 4);
            s16x8 bWc = *(const s16x8*)((const char*)&sWT[0][0] + byteoff);
            s16x8 bWe = *(const s16x8*)((const char*)&sWT[1][0] + byteoff);
            acc[c] = __builtin_amdgcn_mfma_f32_16x16x32_bf16(sf[kb], bWc, acc[c], 0, 0, 0);
            acc[c] = __builtin_amdgcn_mfma_f32_16x16x32_bf16(wf[kb], bWe, acc[c], 0, 0, 0);
        }
    }

    float o[4][4];
    float ssq[4] = {0.f, 0.f, 0.f, 0.f};
    #pragma unroll
    for (int c = 0; c < 4; c++) {
        #pragma unroll
        for (int r = 0; r < 4; r++) {
            float x = acc[c][r];
            float y = (x > 0.f) ? x : 0.2f * x;
            o[c][r] = y;
            ssq[r] += y * y;
        }
    }
    #pragma unroll
    for (int r = 0; r < 4; r++) {
        ssq[r] += __shfl_xor(ssq[r], 1);
        ssq[r] += __shfl_xor(ssq[r], 2);
        ssq[r] += __shfl_xor(ssq[r], 4);
        ssq[r] += __shfl_xor(ssq[r], 8);
    }

    __syncthreads();   // all reads of sWT/sS done -> reuse as scratch

    float* scrF = (float*)&sWT[0][0];           // [64][64] f32 normalized
    unsigned short* scrH = &sS[0];              // [64][64] bf16 unnormalized
    #pragma unroll
    for (int r = 0; r < 4; r++) {
        float sc = 1.0f / fmaxf(sqrtf(ssq[r]), 1e-12f);
        int lrow = wid * 16 + lg * 4 + r;
        #pragma unroll
        for (int c = 0; c < 4; c++) {
            scrF[lrow * 64 + c * 16 + lr] = o[c][r] * sc;
            if (!LAST) scrH[lrow * 64 + c * 16 + lr] = f2bf(o[c][r]);
        }
    }

    __syncthreads();   // scratch filled

    // fully-coalesced writeback
    #pragma unroll
    for (int i = 0; i < 4; i++) {
        int c16 = tid + 256 * i;                // 0..1023
        int lrow = c16 >> 4, c4 = c16 & 15;
        int row = n0 + lrow;
        if (row < NN) {
            f32x4 v = *(const f32x4*)(scrF + lrow * 64 + c4 * 4);
            __builtin_nontemporal_store(v, (f32x4*)(outN + (size_t)row * OS) + c4);
        }
    }
    if (!LAST) {
        #pragma unroll
        for (int i = 0; i < 2; i++) {
            int ch = tid + 256 * i;             // 0..511
            int lrow = ch >> 3, h8 = ch & 7;
            int row = n0 + lrow;
            if (row < NN)
                *(s16x8*)(ebf_out + (size_t)row * D + h8 * 8) =
                    *(const s16x8*)(scrH + lrow * 64 + h8 * 8);
        }
    }
}

extern "C" void kernel_launch(void* const* d_in, const int* in_sizes, int n_in,
                              void* d_out, int out_size, void* d_ws, size_t ws_size,
                              hipStream_t stream) {
    const int*   rows = (const int*)d_in[0];
    const int*   cols = (const int*)d_in[1];
    const float* vals = (const float*)d_in[2];
    const float* ue   = (const float*)d_in[3];
    const float* ie   = (const float*)d_in[4];
    const float* Wc   = (const float*)d_in[5];
    const float* bc   = (const float*)d_in[6];
    const float* We   = (const float*)d_in[7];
    const float* be   = (const float*)d_in[8];
    float* out = (float*)d_out;

    // ws layout (~136 MB): eb0, eb1, cnt+ecv16 (one zeroed span), ecvT, W images.
    unsigned short* eb0 = (unsigned short*)d_ws;            // NN*D bf16 (38.4MB)
    unsigned short* eb1 = eb0 + (size_t)NN * D;             // NN*D bf16 (38.4MB)
    int*   cnt    = (int*)(eb1 + (size_t)NN * D);           // NN (1.2MB)
    unsigned long long* ecv16 = (unsigned long long*)(cnt + NN);     // NN*16 (38.4MB)
    unsigned long long* ecvT  = ecv16 + (size_t)NN * 16;             // NN*8 (19.2MB)
    unsigned short* wbf = (unsigned short*)(ecvT + (size_t)NN * 8);  // 48KB

    // zero cnt + ecv16 in one contiguous memset (39.6 MB)
    hipMemsetAsync(cnt, 0, (size_t)NN * sizeof(int) + (size_t)NN * 16 * 8, stream);
    k_concat<<<(NN * 16 + 255) / 256, 256, 0, stream>>>(
        ue, ie, out, eb0, Wc, We, wbf, rows, cols, vals, cnt, ecv16, ecvT);

    const int GB_FUSED = (NN + 63) / 64;
    unsigned short* eb[2] = {eb0, eb1};
    for (int l = 0; l < 3; l++) {
        if (l < 2)
            k_fused<false><<<GB_FUSED, 256, 0, stream>>>(
                cnt, ecv16, ecvT, eb[l & 1], eb[(l + 1) & 1],
                wbf + l * 8192, bc + l * 64, be + l * 64, out + (l + 1) * 64);
        else
            k_fused<true><<<GB_FUSED, 256, 0, stream>>>(
                cnt, ecv16, ecvT, eb[l & 1], nullptr,
                wbf + l * 8192, bc + l * 64, be + l * 64, out + (l + 1) * 64);
    }
}

// Round 26
// 252.731 us; speedup vs baseline: 1.0645x; 1.0645x over previous
//
#include <hip/hip_runtime.h>

#define NU 100000
#define NI 200000
#define NN 300000
#define NNZE 1200000
#define D 64
#define OS 256   // (L+1)*D output row stride
#define EW 24    // total slots: 8 in ecv8 (zeroed) + 16 in ecvT

typedef __attribute__((ext_vector_type(8))) short s16x8;
typedef __attribute__((ext_vector_type(4))) float f32x4;
typedef __attribute__((ext_vector_type(2))) unsigned long long u64x2;

__device__ __forceinline__ float bf2f(unsigned short u) {
    return __uint_as_float(((unsigned int)u) << 16);
}
__device__ __forceinline__ unsigned short f2bf(float f) {
    unsigned int u = __float_as_uint(f);
    u = (u + 0x7FFF + ((u >> 16) & 1)) >> 16;   // RNE
    return (unsigned short)u;
}

// -- concat -> out chunk0 + ebf; fused ELL scatter (first 1.2M threads);
//    blocks 0-5 additionally pre-transpose W --------------------------------
__global__ void k_concat(const float* __restrict__ ue, const float* __restrict__ ie,
                         float* __restrict__ out, unsigned short* __restrict__ ebf,
                         const float* __restrict__ Wc, const float* __restrict__ We,
                         unsigned short* __restrict__ wbf,
                         const int* __restrict__ rows, const int* __restrict__ cols,
                         const float* __restrict__ vals, int* __restrict__ cnt,
                         unsigned long long* __restrict__ ecv8,
                         unsigned long long* __restrict__ ecvT) {
    int idx = blockIdx.x * blockDim.x + threadIdx.x;
    // ELL scatter (latency-bound, hides under the BW-bound concat stream)
    if (idx < NNZE) {
        int r = rows[idx];
        int pos = atomicAdd(&cnt[r], 1);
        // low 32: byte offset into ebf (col*D*2 = col*128); high 32: val bits
        unsigned long long packed = (unsigned int)(cols[idx] * 128)
            | ((unsigned long long)(unsigned int)__float_as_int(vals[idx]) << 32);
        if (pos < 8)       ecv8[(size_t)r * 8 + pos] = packed;
        else if (pos < EW) ecvT[(size_t)r * 16 + (pos - 8)] = packed;
    }
    if (idx < NN * 16) {
        int n = idx >> 4, c = idx & 15;
        float4 v;
        if (n < NU) v = ((const float4*)(ue + (size_t)n * D))[c];
        else        v = ((const float4*)(ie + (size_t)(n - NU) * D))[c];
        f32x4 vv = {v.x, v.y, v.z, v.w};
        __builtin_nontemporal_store(vv, (f32x4*)(out + (size_t)n * OS) + c);
        ushort4 b;
        b.x = f2bf(v.x); b.y = f2bf(v.y); b.z = f2bf(v.z); b.w = f2bf(v.w);
        *(ushort4*)(ebf + (size_t)n * D + c * 4) = b;
    }
    // W pre-transpose -> swizzled bf16 images (6 blocks, independent work)
    if (blockIdx.x < 6) {
        int lm = blockIdx.x;
        int l = lm >> 1, m = lm & 1;
        const float* W = (m ? We : Wc) + l * 4096;
        unsigned short* dst = wbf + lm * 4096;
        int tid = threadIdx.x;
        int base = tid * 16;
        int k = base >> 6, n = base & 63;
        #pragma unroll
        for (int i = 0; i < 4; i++) {
            float4 v = *(const float4*)(W + k * 64 + n + i * 4);
            #pragma unroll
            for (int j = 0; j < 4; j++) {
                int col = n + i * 4 + j;
                int byteoff = (col * 128 + k * 2) ^ ((col & 7) << 4);
                float fv = (j == 0) ? v.x : (j == 1) ? v.y : (j == 2) ? v.z : v.w;
                *(unsigned short*)((char*)dst + byteoff) = f2bf(fv);
            }
        }
    }
}

// ---------------- fused layer: ELL SpMM (8 lanes x 16B) + MFMA dense ---------
template<bool LAST>
__global__ __launch_bounds__(256, 4) void k_fused(
    const int* __restrict__ cnt, const unsigned long long* __restrict__ ecv8,
    const unsigned long long* __restrict__ ecvT,
    const unsigned short* __restrict__ ebf_in, unsigned short* __restrict__ ebf_out,
    const unsigned short* __restrict__ wsrc,
    const float* __restrict__ bc, const float* __restrict__ be,
    float* __restrict__ outN) {
    __shared__ __align__(16) unsigned short sWT[2][64 * 64];  // W^T; later f32 scratch
    __shared__ __align__(16) unsigned short sS[64 * 64];      // side tile; later bf16 scratch

    int tid = threadIdx.x;
    int n0 = blockIdx.x * 64;
    int grp = tid >> 3, lane8 = tid & 7;    // 32 groups x 8 lanes; 2 rows/group

    // deg load issued here; its VALUE is only needed at the rare tail branch
    int R0 = n0 + grp * 2;
    int deg[2];
    #pragma unroll
    for (int r = 0; r < 2; r++) {
        int rr = R0 + r;
        deg[r] = (rr < NN) ? cnt[rr] : 0;
    }

    // stage W: linear 16KB vector copy (swizzle baked into the image)
    {
        unsigned short* dst = &sWT[0][0];
        #pragma unroll
        for (int i = 0; i < 4; i++) {
            int idx = i * 2048 + tid * 8;
            *(s16x8*)(dst + idx) = *(const s16x8*)(wsrc + idx);
        }
    }

    // SpMM: 2 rows/group; round 1 = 8 UNCONDITIONAL slots (zero-padded ELL),
    // so metadata loads issue in parallel with the deg load. Tail is rare.
    {
        const char* ebase_c = (const char*)ebf_in;
        #pragma unroll
        for (int rr = 0; rr < 2; rr++) {
            int lrow = grp * 2 + rr;
            float a[8];
            #pragma unroll
            for (int j = 0; j < 8; j++) a[j] = 0.f;

            // clamp: rows >= NN read row NN-1's (valid, zero-padded) slots;
            // results are discarded by the row<NN guards downstream.
            int rclamp = (R0 + rr) < NN ? (R0 + rr) : (NN - 1);
            const unsigned long long* b8 = ecv8 + (size_t)rclamp * 8;
            unsigned long long e[8];
            {   // branchless 64B metadata read -> 4x16B loads
                u64x2 p0 = *(const u64x2*)(b8 + 0);
                u64x2 p1 = *(const u64x2*)(b8 + 2);
                u64x2 p2 = *(const u64x2*)(b8 + 4);
                u64x2 p3 = *(const u64x2*)(b8 + 6);
                e[0] = p0.x; e[1] = p0.y; e[2] = p1.x; e[3] = p1.y;
                e[4] = p2.x; e[5] = p2.y; e[6] = p3.x; e[7] = p3.y;
            }
            s16x8 gg[8];
            float v[8];
            #pragma unroll
            for (int k = 0; k < 8; k++) {
                unsigned int boff = (unsigned int)(e[k] & 0xFFFFFFFFu);
                v[k] = __int_as_float((int)(e[k] >> 32));
                gg[k] = *(const s16x8*)(ebase_c + boff + lane8 * 16);
            }
            #pragma unroll
            for (int k = 0; k < 8; k++)
                #pragma unroll
                for (int j = 0; j < 8; j++)
                    a[j] += v[k] * bf2f((unsigned short)gg[k][j]);

            // rare tail (P(deg>8) ~ 2%)
            int dg = deg[rr] > EW ? EW : deg[rr];
            if (dg > 8) {
                const unsigned long long* bt = ecvT + (size_t)rclamp * 16;
                for (int i = 8; i < dg; i += 8) {
                    #pragma unroll
                    for (int k = 0; k < 8; k++)
                        e[k] = (i + k < dg) ? bt[i - 8 + k] : 0ull;
                    #pragma unroll
                    for (int k = 0; k < 8; k++) {
                        unsigned int boff = (unsigned int)(e[k] & 0xFFFFFFFFu);
                        v[k] = __int_as_float((int)(e[k] >> 32));
                        gg[k] = *(const s16x8*)(ebase_c + boff + lane8 * 16);
                    }
                    #pragma unroll
                    for (int k = 0; k < 8; k++)
                        #pragma unroll
                        for (int j = 0; j < 8; j++)
                            a[j] += v[k] * bf2f((unsigned short)gg[k][j]);
                }
            }

            s16x8 r8;
            #pragma unroll
            for (int j = 0; j < 8; j++) r8[j] = (short)f2bf(a[j]);
            int byteoff = (lrow * 128 + lane8 * 16) ^ ((lrow & 7) << 4);
            *(s16x8*)((char*)&sS[0] + byteoff) = r8;
        }
    }

    int wid = tid >> 6, lane = tid & 63;
    int lg = lane >> 4, lr = lane & 15;

    __syncthreads();   // sS (and sWT) ready

    int rowA = n0 + wid * 16 + lr;
    int rowAc = rowA < NN ? rowA : NN - 1;
    size_t abase = (size_t)rowAc * D;
    s16x8 ef[2];
    ef[0] = *(const s16x8*)(ebf_in + abase + lg * 8);
    ef[1] = *(const s16x8*)(ebf_in + abase + 32 + lg * 8);

    f32x4 acc[4];
    #pragma unroll
    for (int c = 0; c < 4; c++) {
        float bj = bc[c * 16 + lr] + be[c * 16 + lr];
        acc[c] = (f32x4){bj, bj, bj, bj};
    }

    int lrowA = wid * 16 + lr;
    s16x8 sf[2], wf[2];
    #pragma unroll
    for (int kb = 0; kb < 2; kb++) {
        int byteoff = (lrowA * 128 + (kb * 32 + lg * 8) * 2) ^ ((lrowA & 7) << 4);
        sf[kb] = *(const s16x8*)((const char*)&sS[0] + byteoff);
        #pragma unroll
        for (int j = 0; j < 8; j++) {
            float p = bf2f((unsigned short)sf[kb][j]) * bf2f((unsigned short)ef[kb][j]);
            wf[kb][j] = (short)f2bf(p);
        }
    }

    #pragma unroll
    for (int c = 0; c < 4; c++) {
        #pragma unroll
        for (int kb = 0; kb < 2; kb++) {
            int row = c * 16 + lr;
            int byteoff = (row * 128 + (kb * 32 + lg * 8) * 2) ^ ((row & 7) << 4);
            s16x8 bWc = *(const s16x8*)((const char*)&sWT[0][0] + byteoff);
            s16x8 bWe = *(const s16x8*)((const char*)&sWT[1][0] + byteoff);
            acc[c] = __builtin_amdgcn_mfma_f32_16x16x32_bf16(sf[kb], bWc, acc[c], 0, 0, 0);
            acc[c] = __builtin_amdgcn_mfma_f32_16x16x32_bf16(wf[kb], bWe, acc[c], 0, 0, 0);
        }
    }

    float o[4][4];
    float ssq[4] = {0.f, 0.f, 0.f, 0.f};
    #pragma unroll
    for (int c = 0; c < 4; c++) {
        #pragma unroll
        for (int r = 0; r < 4; r++) {
            float x = acc[c][r];
            float y = (x > 0.f) ? x : 0.2f * x;
            o[c][r] = y;
            ssq[r] += y * y;
        }
    }
    #pragma unroll
    for (int r = 0; r < 4; r++) {
        ssq[r] += __shfl_xor(ssq[r], 1);
        ssq[r] += __shfl_xor(ssq[r], 2);
        ssq[r] += __shfl_xor(ssq[r], 4);
        ssq[r] += __shfl_xor(ssq[r], 8);
    }

    __syncthreads();   // all reads of sWT/sS done -> reuse as scratch

    float* scrF = (float*)&sWT[0][0];           // [64][64] f32 normalized
    unsigned short* scrH = &sS[0];              // [64][64] bf16 unnormalized
    #pragma unroll
    for (int r = 0; r < 4; r++) {
        float sc = 1.0f / fmaxf(sqrtf(ssq[r]), 1e-12f);
        int lrow = wid * 16 + lg * 4 + r;
        #pragma unroll
        for (int c = 0; c < 4; c++) {
            scrF[lrow * 64 + c * 16 + lr] = o[c][r] * sc;
            if (!LAST) scrH[lrow * 64 + c * 16 + lr] = f2bf(o[c][r]);
        }
    }

    __syncthreads();   // scratch filled

    // fully-coalesced writeback
    #pragma unroll
    for (int i = 0; i < 4; i++) {
        int c16 = tid + 256 * i;                // 0..1023
        int lrow = c16 >> 4, c4 = c16 & 15;
        int row = n0 + lrow;
        if (row < NN) {
            f32x4 v = *(const f32x4*)(scrF + lrow * 64 + c4 * 4);
            __builtin_nontemporal_store(v, (f32x4*)(outN + (size_t)row * OS) + c4);
        }
    }
    if (!LAST) {
        #pragma unroll
        for (int i = 0; i < 2; i++) {
            int ch = tid + 256 * i;             // 0..511
            int lrow = ch >> 3, h8 = ch & 7;
            int row = n0 + lrow;
            if (row < NN)
                *(s16x8*)(ebf_out + (size_t)row * D + h8 * 8) =
                    *(const s16x8*)(scrH + lrow * 64 + h8 * 8);
        }
    }
}

extern "C" void kernel_launch(void* const* d_in, const int* in_sizes, int n_in,
                              void* d_out, int out_size, void* d_ws, size_t ws_size,
                              hipStream_t stream) {
    const int*   rows = (const int*)d_in[0];
    const int*   cols = (const int*)d_in[1];
    const float* vals = (const float*)d_in[2];
    const float* ue   = (const float*)d_in[3];
    const float* ie   = (const float*)d_in[4];
    const float* Wc   = (const float*)d_in[5];
    const float* bc   = (const float*)d_in[6];
    const float* We   = (const float*)d_in[7];
    const float* be   = (const float*)d_in[8];
    float* out = (float*)d_out;

    // ws layout (~136 MB): eb0, eb1, cnt+ecv8 (one zeroed span), ecvT, W images.
    unsigned short* eb0 = (unsigned short*)d_ws;            // NN*D bf16 (38.4MB)
    unsigned short* eb1 = eb0 + (size_t)NN * D;             // NN*D bf16 (38.4MB)
    int*   cnt    = (int*)(eb1 + (size_t)NN * D);           // NN (1.2MB)
    unsigned long long* ecv8 = (unsigned long long*)(cnt + NN);      // NN*8 (19.2MB)
    unsigned long long* ecvT = ecv8 + (size_t)NN * 8;                // NN*16 (38.4MB)
    unsigned short* wbf = (unsigned short*)(ecvT + (size_t)NN * 16); // 48KB

    // zero cnt + ecv8 in one contiguous memset (20.4 MB)
    hipMemsetAsync(cnt, 0, (size_t)NN * sizeof(int) + (size_t)NN * 8 * 8, stream);
    k_concat<<<(NN * 16 + 255) / 256, 256, 0, stream>>>(
        ue, ie, out, eb0, Wc, We, wbf, rows, cols, vals, cnt, ecv8, ecvT);

    const int GB_FUSED = (NN + 63) / 64;
    unsigned short* eb[2] = {eb0, eb1};
    for (int l = 0; l < 3; l++) {
        if (l < 2)
            k_fused<false><<<GB_FUSED, 256, 0, stream>>>(
                cnt, ecv8, ecvT, eb[l & 1], eb[(l + 1) & 1],
                wbf + l * 8192, bc + l * 64, be + l * 64, out + (l + 1) * 64);
        else
            k_fused<true><<<GB_FUSED, 256, 0, stream>>>(
                cnt, ecv8, ecvT, eb[l & 1], nullptr,
                wbf + l * 8192, bc + l * 64, be + l * 64, out + (l + 1) * 64);
    }
}